// Round 1
// 309.387 us; speedup vs baseline: 1.0167x; 1.0167x over previous
//
#include <hip/hip_runtime.h>
#include <hip/hip_bf16.h>
#include <cmath>

// Problem constants
#define B_    4
#define T_    1000000
#define E_    8
#define C_    128
#define NCH   512        // fused conv output channels (both branches, 2*256)
#define KK    4096       // GEMM K = E * kernel (8*512); windows are contiguous rows
#define TOUT  1953       // (1e6 - 512)/512 + 1
#define TP    1956       // padded t stride (mult of 4) for aligned float4 stores
#define TPAD  2048       // padded t rows per batch in xb2 (zero-filled past 1952)
#define NT2   31         // ceil(1953/64) tiles of 64 along t

typedef __attribute__((ext_vector_type(8))) short bf16x8;   // 8 bf16 = 4 VGPRs
typedef __attribute__((ext_vector_type(4))) float f32x4;

__device__ __forceinline__ float sigmoidf_(float v) { return 1.f / (1.f + __expf(-v)); }

// async 16B/lane global->LDS copy: LDS dest = uniform base + lane*16
__device__ __forceinline__ void gload_lds16(const __hip_bfloat16* g, __hip_bfloat16* l) {
  __builtin_amdgcn_global_load_lds(
      (const __attribute__((address_space(1))) void*)(const void*)g,
      (__attribute__((address_space(3))) void*)(void*)l, 16, 0, 0);
}

// ---------------------------------------------------------------------------
// Fragment-ordered operand layout ("frag chunk" = 16 rows x 32 k, stored as
// [lane][8] in exact MFMA A/B operand order: lane = (k>>3 & 3)*16 + (row&15),
// j = k&7). One chunk = 512 elems = 1KB bf16; a fragment load is then ONE
// fully-coalesced global_load_dwordx4 per lane (lane*16B).
// xb2: [b][tt=t/16][kc=k/32][lane][8]   (b*2^23 elements per batch)
// Wn2: [nt=n/16][kc][lane][8]
//
// Kernel A: merged input prep, one launch.
//  - blocks [0,512): weight prep for channel n (LDS transpose of (e,kpos)->k)
//  - blocks [512, 512+16384): x fp32 -> bf16 frag-ordered, zero pad t>=TOUT
__global__ __launch_bounds__(256) void prep_inputs(
    const float* __restrict__ x,
    const float* __restrict__ wc, const float* __restrict__ bc,
    const float* __restrict__ wm, const float* __restrict__ bm,
    __hip_bfloat16* __restrict__ xb2, __hip_bfloat16* __restrict__ Wn2,
    float* __restrict__ bias_t) {
  __shared__ float row[KK];
  const int bid = blockIdx.x;
  if (bid < NCH) {
    const int n = bid, br = n >> 8, o = n & 255;
    const float* wsrc = (br ? wm : wc) + (size_t)o * KK;
    for (int i = threadIdx.x; i < KK; i += 256) row[i] = wsrc[i];   // [e][kpos]
    __syncthreads();
    const int nt = n >> 4, nr = n & 15;
    for (int k = threadIdx.x; k < KK; k += 256) {
      int kpos = k >> 3, e = k & 7;                 // W[n][k] with k = kpos*8+e
      size_t addr = (((size_t)nt * 128 + (k >> 5)) * 64
                     + (size_t)((k >> 3) & 3) * 16 + nr) * 8 + (k & 7);
      Wn2[addr] = __float2bfloat16(row[e * 512 + kpos]);
    }
    if (threadIdx.x == 0) bias_t[n] = (br ? bm : bc)[o];
  } else {
    size_t gid = (size_t)(bid - NCH) * 256 + threadIdx.x;
    size_t idx8 = gid * 8;                       // element index in [4][2^23]
    size_t b = idx8 >> 23, rem = idx8 & ((1ull << 23) - 1);
    int lane = (int)((rem >> 3) & 63);
    int kc   = (int)((rem >> 9) & 127);
    int tt   = (int)(rem >> 16);
    int t = tt * 16 + (lane & 15);
    int k = kc * 32 + (lane >> 4) * 8;
    union { __hip_bfloat16 h[8]; uint4 u; } o;
    if (t < TOUT) {
      const float* src = x + b * 8000000ull + (size_t)t * KK + k;
      float4 f0 = *(const float4*)(src);
      float4 f1 = *(const float4*)(src + 4);
      o.h[0] = __float2bfloat16(f0.x); o.h[1] = __float2bfloat16(f0.y);
      o.h[2] = __float2bfloat16(f0.z); o.h[3] = __float2bfloat16(f0.w);
      o.h[4] = __float2bfloat16(f1.x); o.h[5] = __float2bfloat16(f1.y);
      o.h[6] = __float2bfloat16(f1.z); o.h[7] = __float2bfloat16(f1.w);
    } else {
      o.u = make_uint4(0, 0, 0, 0);
    }
    *(uint4*)(xb2 + idx8) = o.u;
  }
}

// ---------------------------------------------------------------------------
// Kernel C (R5): LDS-staged double-buffered GEMM. C[t,n] = sum_k A[t,k]W[n,k].
// Block = 512 thr = 8 waves (4 t-waves x 2 n-waves), block tile 128x128,
// wave tile 32t x 64n (acc 2x4 of 16x16). BK=64 per buffer (2 kc chunks).
// A-tile and B-tile are each staged ONCE per block into LDS via
// global_load_lds width=16 (vs the old register-direct design that pulled
// A x2 and B x4 from L2 = 6 MB/block; now 2 MB/block -> L2 floor 47->15us).
// LDS layout = the frag-chunk order itself: chunk slot c (0..15 A, 16..31 B)
// at lds[buf] + c*512 elems; gload_lds dest (uniform base + lane*16B) matches
// the [lane][8] chunk layout exactly, so fragment ds_read_b128 at lane*16B is
// stride-1 conflict-free. m97-structure 2-barrier loop: stage next buffer,
// ds_read + 16 MFMA on current, __syncthreads (drains vmcnt+lgkm).
// Grid 256 = 1 block/CU; XCD swizzle: 4 n-groups of one (t,b) share
// L%8 = XCD so A staging hits that XCD's L2 (R4: FETCH 254->82MB proof).
__global__ __launch_bounds__(512, 2) void mfma_gemm(
    const __hip_bfloat16* __restrict__ xb2, const __hip_bfloat16* __restrict__ Wn2,
    float* __restrict__ u2) {
  __shared__ __hip_bfloat16 lds[2][16384];   // 2 bufs x (A 16KB + B 16KB)

  const int tid  = threadIdx.x;
  const int lane = tid & 63, wave = tid >> 6;
  const int wt = wave & 3, wn = wave >> 2;

  // Swizzle: L = xcd + 8*(nb + 4*sh); s = sh*8 + xcd = (t,b) group 0..63.
  const int L   = blockIdx.x;
  const int xcd = L & 7;
  const int r   = L >> 3;
  const int nb  = r & 3;
  const int sh  = r >> 2;                 // 0..7
  const int s   = sh * 8 + xcd;           // 0..63
  const int tblk = s & 15, b = s >> 4;
  const int t0 = tblk * 128, n0 = nb * 128;

  const size_t FR = 512;                  // elems per frag chunk

  // This wave's 4 staging chunk slots: c = wave*4 + s2, s2 in [0,4).
  //   c <  16: A chunk, row = b*128 + tblk*8 + (c>>1), kc2 = c&1
  //   c >= 16: B chunk, row = nb*8 + ((c-16)>>1),      kc2 = c&1
  // Per-lane global src (elements), before the per-step kc0*512 advance:
  const __hip_bfloat16* gsrc[4];
  int cslot[4];
#pragma unroll
  for (int s2 = 0; s2 < 4; ++s2) {
    int c = wave * 4 + s2;
    cslot[c & 3] = c;                     // c&3 == s2 (wave*4 aligned)
    if (c < 16) {
      gsrc[s2] = xb2 + ((size_t)(b * 128 + tblk * 8 + (c >> 1)) * 128 + (c & 1)) * FR
                 + (size_t)lane * 8;
    } else {
      gsrc[s2] = Wn2 + ((size_t)(nb * 8 + ((c - 16) >> 1)) * 128 + (c & 1)) * FR
                 + (size_t)lane * 8;
    }
  }

  f32x4 acc[2][4];
#pragma unroll
  for (int i = 0; i < 2; ++i)
#pragma unroll
    for (int j = 0; j < 4; ++j) acc[i][j] = (f32x4)(0.0f);

  // Stage one BK=64 buffer (32 chunks, 4 per wave): step covers kc = 2*step,
  // 2*step+1 -> global advance = step*1024 elements (kc2 folded into gsrc).
  auto STAGE = [&](int buf, int step) {
#pragma unroll
    for (int s2 = 0; s2 < 4; ++s2) {
      gload_lds16(gsrc[s2] + (size_t)step * 1024, &lds[buf][(size_t)cslot[s2] * FR]);
    }
  };

  auto COMPUTE = [&](int buf) {
    bf16x8 aF[2][2], bF[4][2];
#pragma unroll
    for (int i = 0; i < 2; ++i)
#pragma unroll
      for (int c = 0; c < 2; ++c)
        aF[i][c] = *(const bf16x8*)(&lds[buf][(size_t)((wt * 2 + i) * 2 + c) * FR
                                              + (size_t)lane * 8]);
#pragma unroll
    for (int j = 0; j < 4; ++j)
#pragma unroll
      for (int c = 0; c < 2; ++c)
        bF[j][c] = *(const bf16x8*)(&lds[buf][(size_t)(16 + (wn * 4 + j) * 2 + c) * FR
                                              + (size_t)lane * 8]);
#pragma unroll
    for (int c = 0; c < 2; ++c)
#pragma unroll
      for (int i = 0; i < 2; ++i)
#pragma unroll
        for (int j = 0; j < 4; ++j)
          acc[i][j] = __builtin_amdgcn_mfma_f32_16x16x32_bf16(aF[i][c], bF[j][c],
                                                              acc[i][j], 0, 0, 0);
  };

  // Prologue: fill buffer 0 (barrier drains vmcnt per __syncthreads semantics).
  STAGE(0, 0);
  __syncthreads();

  int cur = 0;
#pragma unroll 1
  for (int step = 0; step < 64; ++step) {
    if (step + 1 < 64) STAGE(cur ^ 1, step + 1);  // issue next-tile loads first
    COMPUTE(cur);                                  // ds_read + 16 MFMA
    __syncthreads();                               // drains vmcnt(0)+lgkmcnt(0)
    cur ^= 1;
  }

  // Epilogue. C/D layout: col = lane&15, row = (lane>>4)*4 + reg.
  const int crow = (lane >> 4) * 4;
  const int ccol = lane & 15;
#pragma unroll
  for (int j = 0; j < 4; ++j) {
    int n = n0 + wn * 64 + j * 16 + ccol;
    float* urow = u2 + ((size_t)n * B_ + b) * TP;
#pragma unroll
    for (int i = 0; i < 2; ++i) {
      int t = t0 + wt * 32 + i * 16 + crow;    // mult of 4
      if (t < TOUT) *(f32x4*)(urow + t) = acc[i][j];  // may touch pad [1953,1956)
    }
  }
}

// ---------------------------------------------------------------------------
// Kernel 2: bias + GLU (on load from u2) -> 1x1 share conv + leaky.
// br==1: store h_main; br==0: per-tile max over t -> gct_part.
__global__ __launch_bounds__(256) void share_act(
    const float* __restrict__ u2, const float* __restrict__ bias_t,
    const float* __restrict__ wsc, const float* __restrict__ bsc,
    const float* __restrict__ wsm, const float* __restrict__ bsm,
    float* __restrict__ hmain, float* __restrict__ gct_part) {
  __shared__ float Wl[128 * 132];   // Wl[cp*132 + cout] = ws[cout, cp]
  __shared__ float ul[128 * 68];    // ul[cp*68 + t]
  const int tid  = threadIdx.x;
  const int tile = blockIdx.x;      // 0..30
  const int b    = blockIdx.y;
  const int br   = blockIdx.z;
  const int t0   = tile * 64;
  const float* ws = br ? wsm : wsc;
  const float* bs = br ? bsm : bsc;

  for (int g = tid; g < 16384; g += 256) {
    int co = g >> 7, cp = g & 127;
    Wl[cp * 132 + co] = ws[g];
  }
  const size_t base_v = ((size_t)(br * 256) * B_ + b) * TP;
  const size_t base_g = ((size_t)(br * 256 + 128) * B_ + b) * TP;
  for (int g = tid; g < 8192; g += 256) {
    int cp = g >> 6, t = g & 63;
    float v = 0.f;
    if (t0 + t < TOUT) {
      float va = u2[base_v + (size_t)cp * B_ * TP + t0 + t] + bias_t[br * 256 + cp];
      float vg = u2[base_g + (size_t)cp * B_ * TP + t0 + t] + bias_t[br * 256 + 128 + cp];
      v = va * sigmoidf_(vg);
    }
    ul[cp * 68 + t] = v;
  }
  __syncthreads();

  const int ty = tid >> 4, tx = tid & 15;  // c-groups x t-groups
  float acc[8][4];
#pragma unroll
  for (int i = 0; i < 8; ++i)
#pragma unroll
    for (int j = 0; j < 4; ++j) acc[i][j] = 0.f;

  for (int cp = 0; cp < 128; ++cp) {
    float4 a0 = *(const float4*)&Wl[cp*132 + ty*4];
    float4 a1 = *(const float4*)&Wl[cp*132 + 64 + ty*4];
    float4 b4 = *(const float4*)&ul[cp*68 + tx*4];
    float av[8] = {a0.x,a0.y,a0.z,a0.w,a1.x,a1.y,a1.z,a1.w};
    float bv[4] = {b4.x,b4.y,b4.z,b4.w};
#pragma unroll
    for (int i = 0; i < 8; ++i)
#pragma unroll
      for (int j = 0; j < 4; ++j) acc[i][j] = fmaf(av[i], bv[j], acc[i][j]);
  }

  float mloc[8];
#pragma unroll
  for (int i = 0; i < 8; ++i) mloc[i] = -INFINITY;
#pragma unroll
  for (int i = 0; i < 8; ++i) {
    int c = (i < 4) ? (ty*4 + i) : (64 + ty*4 + (i - 4));
    float bias = bs[c];
#pragma unroll
    for (int j = 0; j < 4; ++j) {
      int t = t0 + tx*4 + j;
      if (t >= TOUT) continue;
      float v = acc[i][j] + bias;
      v = (v >= 0.f) ? v : 0.01f * v;
      if (br == 1) {
        hmain[((size_t)b * 128 + c) * TOUT + t] = v;
      } else {
        mloc[i] = fmaxf(mloc[i], v);
      }
    }
  }
  if (br == 0) {
    __syncthreads();               // done reading ul; reuse as reduction buffer
    float* red = ul;               // 128*16 region
#pragma unroll
    for (int i = 0; i < 8; ++i) {
      int c = (i < 4) ? (ty*4 + i) : (64 + ty*4 + (i - 4));
      red[c * 16 + tx] = mloc[i];
    }
    __syncthreads();
    if (tid < 128) {
      float m = -INFINITY;
#pragma unroll
      for (int k = 0; k < 16; ++k) m = fmaxf(m, red[tid * 16 + k]);
      gct_part[((size_t)b * 128 + tid) * NT2 + tile] = m;
    }
  }
}

// ---------------------------------------------------------------------------
// Kernel 3: gct = max over tiles; q = tanh(gct @ Wp^T + bp). One block per b.
__global__ void gct_q(const float* __restrict__ gct_part, const float* __restrict__ wp,
                      const float* __restrict__ bp, float* __restrict__ q) {
  int b = blockIdx.x, tid = threadIdx.x;   // 128 threads
  __shared__ float g[128];
  float m = -INFINITY;
  for (int tl = 0; tl < NT2; ++tl) m = fmaxf(m, gct_part[((size_t)b * 128 + tid) * NT2 + tl]);
  g[tid] = m;
  __syncthreads();
  float s = bp[tid];
  for (int c = 0; c < 128; ++c) s = fmaf(g[c], wp[tid * 128 + c], s);
  q[b * 128 + tid] = tanhf(s);
}

// ---------------------------------------------------------------------------
// Kernel 4: gate[t] = sigmoid(sum_c h*q); out_part = per-tile max_t h*gate.
__global__ __launch_bounds__(256) void gate_max(
    const float* __restrict__ hmain, const float* __restrict__ q,
    float* __restrict__ out_part) {
  __shared__ float hl[128 * 68];
  __shared__ float ql[128];
  __shared__ float red[256];
  __shared__ float gl[64];
  int tid = threadIdx.x, tile = blockIdx.x, b = blockIdx.y;
  int t0 = tile * 64;
  for (int g = tid; g < 8192; g += 256) {
    int c = g >> 6, t = g & 63;
    hl[c * 68 + t] = (t0 + t < TOUT) ? hmain[((size_t)b * 128 + c) * TOUT + t0 + t] : 0.f;
  }
  if (tid < 128) ql[tid] = q[b * 128 + tid];
  __syncthreads();
  {
    int t = tid & 63, cy = tid >> 6;
    float s = 0.f;
#pragma unroll
    for (int cc = 0; cc < 32; ++cc) s = fmaf(hl[(cy * 32 + cc) * 68 + t], ql[cy * 32 + cc], s);
    red[cy * 64 + t] = s;
  }
  __syncthreads();
  if (tid < 64) {
    float s = red[tid] + red[64 + tid] + red[128 + tid] + red[192 + tid];
    gl[tid] = sigmoidf_(s);
  }
  __syncthreads();
  {
    int c = tid >> 1, th = tid & 1;
    float m = -INFINITY;
#pragma unroll
    for (int tt = 0; tt < 32; ++tt) {
      int t = th * 32 + tt;
      if (t0 + t < TOUT) m = fmaxf(m, hl[c * 68 + t] * gl[t]);
    }
    red[c * 2 + th] = m;
  }
  __syncthreads();
  if (tid < 128) out_part[((size_t)b * 128 + tid) * NT2 + tile] = fmaxf(red[tid * 2], red[tid * 2 + 1]);
}

// ---------------------------------------------------------------------------
// Kernel 5: final max over tiles -> d_out (B,C) row-major.
__global__ void final_max(const float* __restrict__ out_part, float* __restrict__ out) {
  int idx = blockIdx.x * 256 + threadIdx.x;
  if (idx < 512) {
    float m = -INFINITY;
    for (int tl = 0; tl < NT2; ++tl) m = fmaxf(m, out_part[(size_t)idx * NT2 + tl]);
    out[idx] = m;
  }
}

// ---------------------------------------------------------------------------
extern "C" void kernel_launch(void* const* d_in, const int* in_sizes, int n_in,
                              void* d_out, int out_size, void* d_ws, size_t ws_size,
                              hipStream_t stream) {
  const float* x      = (const float*)d_in[0];
  const float* ctx_w  = (const float*)d_in[1];
  const float* ctx_b  = (const float*)d_in[2];
  const float* ctx_sw = (const float*)d_in[3];
  const float* ctx_sb = (const float*)d_in[4];
  const float* main_w = (const float*)d_in[5];
  const float* main_b = (const float*)d_in[6];
  const float* main_sw= (const float*)d_in[7];
  const float* main_sb= (const float*)d_in[8];
  const float* gp_w   = (const float*)d_in[9];
  const float* gp_b   = (const float*)d_in[10];

  char* w = (char*)d_ws;
  __hip_bfloat16* xb2 = (__hip_bfloat16*)(w);              // 4*2^23*2   = 67,108,864
  __hip_bfloat16* Wn2 = (__hip_bfloat16*)(w + 67108864);   // 512*4096*2 =  4,194,304
  float* bias_t  = (float*)(w + 71303168);                 // 512*4
  float* u2      = (float*)(w + 71305216);                 // 512*4*TP*4 = 16,023,552
  float* hmain   = (float*)(w + 87328768);                 // 4*128*1953*4 = 3,999,744
  float* gct_part= (float*)(w + 91328512);                 // 4*128*31*4 = 63,488
  float* q       = (float*)(w + 91392000);                 // 512*4
  float* out_part= (float*)(w + 91394048);                 // 63,488

  prep_inputs<<<NCH + 16384, 256, 0, stream>>>(x, ctx_w, ctx_b, main_w, main_b,
                                               xb2, Wn2, bias_t);
  mfma_gemm<<<256, 512, 0, stream>>>(xb2, Wn2, u2);
  share_act<<<dim3(NT2, B_, 2), 256, 0, stream>>>(u2, bias_t, ctx_sw, ctx_sb,
                                                  main_sw, main_sb, hmain, gct_part);
  gct_q<<<B_, 128, 0, stream>>>(gct_part, gp_w, gp_b, q);
  gate_max<<<dim3(NT2, B_), 256, 0, stream>>>(hmain, q, out_part);
  final_max<<<2, 256, 0, stream>>>(out_part, (float*)d_out);
}